// Round 7
// baseline (212.301 us; speedup 1.0000x reference)
//
#include <hip/hip_runtime.h>
#include <hip/hip_bf16.h>

typedef __hip_bfloat16 bf16;
typedef __attribute__((ext_vector_type(8))) short short8;   // 8 bf16 = 4 VGPRs
typedef __attribute__((ext_vector_type(4))) float f32x4;

#define BATCH 2
#define SEQ   2048
#define HDIM  1024
#define NHEAD 16
#define DHEAD 64
#define MROWS (BATCH*SEQ)   // 4096

// scale folded into Q: (1/sqrt(64)) * log2(e)  -> softmax done in 2^x domain
#define QSCALE 0.18033688f
#define EXP2F(x) __builtin_amdgcn_exp2f(x)

static __device__ __forceinline__ short f2bs(float x) {
    __hip_bfloat16 h = (__hip_bfloat16)x;   // RNE convert
    return *reinterpret_cast<short*>(&h);
}
static __device__ __forceinline__ unsigned int pk2(float a, float b) {
    __hip_bfloat162 h = __float22bfloat162_rn(make_float2(a, b));
    return *reinterpret_cast<unsigned int*>(&h);   // v_cvt_pk; low short = a
}

// async global->LDS, 16B per lane; lane l lands at base + l*16.
static __device__ __forceinline__ void gload16(const void* g, void* l) {
    __builtin_amdgcn_global_load_lds(
        (const __attribute__((address_space(1))) unsigned int*)g,
        (__attribute__((address_space(3))) unsigned int*)l, 16, 0, 0);
}

// ---------------------------------------------------------------------------
// prep1: blocks 0..4095 convert src fp32->bf16 into Sb; blocks 4096..5119
// transpose all four weights: Wq,Wk,Wv into WT rows wsel*1024+n (WT lives in
// d_out scratch, dead until gemm_o overwrites it), Wo into WoT (slot).
// ---------------------------------------------------------------------------
__global__ __launch_bounds__(256) void prep1(const float* __restrict__ src,
        const float* __restrict__ Wq, const float* __restrict__ Wk,
        const float* __restrict__ Wv, const float* __restrict__ Wo,
        short* __restrict__ Sb, short* __restrict__ WT,
        short* __restrict__ WoT)
{
    __shared__ float t[64][65];
    const int bx = blockIdx.x, tid = threadIdx.x;
    if (bx < 4096) {                       // cvt: 4096*256 float4 = 4M elems
        int i = bx * 256 + tid;
        float4 v = ((const float4*)src)[i];
        ushort4 o;
        o.x = (unsigned short)f2bs(v.x);
        o.y = (unsigned short)f2bs(v.y);
        o.z = (unsigned short)f2bs(v.z);
        o.w = (unsigned short)f2bs(v.w);
        ((ushort4*)Sb)[i] = o;
        return;
    }
    const int tb = bx - 4096;              // [0, 1024)
    const int wsel = tb >> 8;              // 0=Wq 1=Wk 2=Wv 3=Wo
    const float* W = (wsel == 0) ? Wq : (wsel == 1) ? Wk : (wsel == 2) ? Wv : Wo;
    short* dst = (wsel < 3) ? WT : WoT;
    const int roff = (wsel < 3) ? wsel * 1024 : 0;
    const int t8 = tb & 255;
    const int n0 = (t8 & 15) * 64, k0 = (t8 >> 4) * 64;
#pragma unroll
    for (int i = 0; i < 16; i++) {
        int idx = tid + i * 256, r = idx >> 6, c = idx & 63;
        t[r][c] = W[(size_t)(k0 + r) * HDIM + n0 + c];
    }
    __syncthreads();
#pragma unroll
    for (int i = 0; i < 16; i++) {
        int idx = tid + i * 256, c = idx >> 6, r = idx & 63;
        dst[(size_t)(roff + n0 + c) * HDIM + k0 + r] = f2bs(t[r][c]);
    }
}

// ---------------------------------------------------------------------------
// Fused Q|K|V GEMM, 256x128 tile, 512 threads (8 waves, 4M x 2N), BK=32,
// TRIPLE-buffered with 2-ahead prefetch. Evidence (R1..R6): per-K-step time
// is ~1.8us regardless of tile/bytes/BK at 1-deep prefetch -> exposed queued
// load latency. Stage tile kk+2 at iter kk; wait vmcnt(6) (oldest 3 of 9
// outstanding = tile kk), tail vmcnt(3)/vmcnt(0). Buf[(kk+2)%3] was last
// read at iter kk-1 whose end-barrier precedes this stage -> no WAR race.
// MFMA k-order unchanged -> bit-identical output. LDS 3 x 24 KB = 72 KB.
// Region by n0>>10: 0=Q (bias+QSCALE), 1=K (bias), 2=V (bias + per-head
// transposed store into Vt[b][h][d][t]).
// ---------------------------------------------------------------------------
__global__ __launch_bounds__(512, 2) void gemm_qkv(const short* __restrict__ A,
        const short* __restrict__ Bt,
        const float* __restrict__ bq, const float* __restrict__ bk,
        const float* __restrict__ bv,
        short* __restrict__ Qout, short* __restrict__ Kout,
        short* __restrict__ Vtout)
{
    __shared__ short SM[3 * 12288];  // [buf][As 16ch | Bs 8ch] = 3 x 24 KB
    const int tid = threadIdx.x, lane = tid & 63, w = tid >> 6;   // w 0..7
    const int quad = lane >> 4, l15 = lane & 15;
    const int m0 = blockIdx.y * 256, n0 = blockIdx.x * 128;
    const int wr = w >> 1, wc = w & 1;     // 4M x 2N wave grid

    // staging: 24 chunks (16 A + 8 B), 3 per wave; chunk u = 16 rows x 32 k
    const short* gsrc[3];
    short* ldst[3];
#pragma unroll
    for (int i = 0; i < 3; i++) {
        int u = w * 3 + i;
        if (u < 16) {
            gsrc[i] = A + (size_t)(m0 + u * 16 + l15) * HDIM + quad * 8;
            ldst[i] = &SM[u * 512];
        } else {
            int v = u - 16;
            gsrc[i] = Bt + (size_t)(n0 + v * 16 + l15) * HDIM + quad * 8;
            ldst[i] = &SM[8192 + v * 512];
        }
    }

    f32x4 acc[4][4];
#pragma unroll
    for (int i = 0; i < 4; i++)
#pragma unroll
        for (int j = 0; j < 4; j++) acc[i][j] = (f32x4){0.f, 0.f, 0.f, 0.f};

    // prologue: stage tiles 0 and 1 into buffers 0 and 1
#pragma unroll
    for (int i = 0; i < 3; i++) { gload16(gsrc[i], ldst[i]); gsrc[i] += 32; }
#pragma unroll
    for (int i = 0; i < 3; i++) { gload16(gsrc[i], ldst[i] + 12288); gsrc[i] += 32; }

    for (int kk = 0; kk < 32; ++kk) {
        if (kk < 30) {                     // stage tile kk+2 into buf (kk+2)%3
            const int nb = ((kk + 2) % 3) * 12288;
#pragma unroll
            for (int i = 0; i < 3; i++) { gload16(gsrc[i], ldst[i] + nb); gsrc[i] += 32; }
            asm volatile("s_waitcnt vmcnt(6)" ::: "memory");   // tile(kk) landed
        } else if (kk == 30) {
            asm volatile("s_waitcnt vmcnt(3)" ::: "memory");
        } else {
            asm volatile("s_waitcnt vmcnt(0)" ::: "memory");
        }
        __builtin_amdgcn_s_barrier();      // tile(kk) visible to all waves;
                                           // prev compute done (end barrier)
        const short* Asb = &SM[(kk % 3) * 12288];
        const short* Bsb = Asb + 8192;
        short8 af[4], bfr[4];
#pragma unroll
        for (int mi = 0; mi < 4; mi++)
            af[mi] = *(const short8*)&Asb[(wr * 4 + mi) * 512 + lane * 8];
#pragma unroll
        for (int ni = 0; ni < 4; ni++)
            bfr[ni] = *(const short8*)&Bsb[(wc * 4 + ni) * 512 + lane * 8];
#pragma unroll
        for (int mi = 0; mi < 4; mi++)
#pragma unroll
            for (int ni = 0; ni < 4; ni++)
                acc[mi][ni] = __builtin_amdgcn_mfma_f32_16x16x32_bf16(
                                  af[mi], bfr[ni], acc[mi][ni], 0, 0, 0);
        __builtin_amdgcn_s_barrier();      // reads of buf(kk%3) done before
                                           // iter kk+1 stages into it
    }

    const int region = n0 >> 10;                 // 0=Q, 1=K, 2=V
    if (region < 2) {
        const float* bias = region ? bk : bq;
        const float oscale = region ? 1.0f : QSCALE;
        short* C = region ? Kout : Qout;
#pragma unroll
        for (int mi = 0; mi < 4; mi++) {
            int mB = m0 + (wr * 4 + mi) * 16 + quad * 4;
#pragma unroll
            for (int ni = 0; ni < 4; ni++) {
                int nl = (n0 + (wc * 4 + ni) * 16 + l15) & 1023;
                float bb = bias[nl];
#pragma unroll
                for (int r = 0; r < 4; r++)
                    C[(size_t)(mB + r) * HDIM + nl] =
                        f2bs((acc[mi][ni][r] + bb) * oscale);
            }
        }
    } else {                                     // V: transposed store
#pragma unroll
        for (int mi = 0; mi < 4; mi++) {
            int mB = m0 + (wr * 4 + mi) * 16 + quad * 4;
            int bb = mB >> 11, t = mB & 2047;
#pragma unroll
            for (int ni = 0; ni < 4; ni++) {
                int n = n0 + (wc * 4 + ni) * 16 + l15;   // 2048..3071
                int h = (n >> 6) & 15, d = n & 63;
                float bvv = bv[n & 1023];
                size_t base = ((size_t)((bb * NHEAD + h) * DHEAD + d)) * SEQ + t;
                ushort4 pk;
                pk.x = (unsigned short)f2bs(acc[mi][ni][0] + bvv);
                pk.y = (unsigned short)f2bs(acc[mi][ni][1] + bvv);
                pk.z = (unsigned short)f2bs(acc[mi][ni][2] + bvv);
                pk.w = (unsigned short)f2bs(acc[mi][ni][3] + bvv);
                *(ushort4*)(Vtout + base) = pk;
            }
        }
    }
}

// ---------------------------------------------------------------------------
// MFMA causal flash attention, TRIPLE-buffered K/V staging with 2-ahead
// prefetch (same depth fix): stage tile it+2 at iter it; wait vmcnt(8)
// (oldest 4 of 12 outstanding = tile it), tails vmcnt(4)/vmcnt(0).
// s_setprio(1) around MFMA clusters. Fixed-max softmax (p = 2^s).
// LDS: 3 x 16 KB K|V buffers + 9 KB P = 57 KB.
// ---------------------------------------------------------------------------
__global__ __launch_bounds__(256) void attn_mfma(const short* __restrict__ Qb,
        const short* __restrict__ Kb, const short* __restrict__ Vt,
        short* __restrict__ Ab)
{
    __shared__ short SMEM[29184];        // [3][8192] K|V tbuf | Ps 4x1152
    const int tid = threadIdx.x, lane = tid & 63, w = tid >> 6;
    const int quad = lane >> 4, l15 = lane & 15;
    const int L = blockIdx.x;

    // xcd = L%8 fixed per (b,head); strip = 31-(L>>5) (longest first)
    const int pair = (L & 7) + 8 * ((L >> 3) & 3);   // 0..31
    const int strip = 31 - (L >> 5);                 // 0..31
    const int b = pair >> 4, head = pair & 15;

    const short* Kbh = Kb + (size_t)b * SEQ * HDIM + head * DHEAD;
    const short* Vth = Vt + (size_t)(b * NHEAD + head) * DHEAD * SEQ;
    short* Pw = SMEM + 24576 + w * 1152;

    const int qbase = strip * 64;
    const int qr = qbase + w * 16 + l15;

    const short* qptr = Qb + (size_t)(b * SEQ + qr) * HDIM + head * DHEAD + quad * 8;
    short8 bq0 = *(const short8*)qptr;
    short8 bq1 = *(const short8*)(qptr + 32);

    // staging pointers: 4 chunks per wave (u<8: K, u>=8: V), incremented
    const short* gp[4];
    int stp[4], ldo[4];
#pragma unroll
    for (int i = 0; i < 4; i++) {
        int u = w * 4 + i;
        if (u < 8) {
            int t = u >> 1, h = u & 1;
            gp[i] = Kbh + (size_t)(t * 16 + l15) * HDIM + h * 32 + quad * 8;
            stp[i] = 64 * HDIM;
        } else {
            int c = u - 8, dt = c >> 1, kh = c & 1;
            gp[i] = Vth + (size_t)(dt * 16 + l15) * SEQ + kh * 32 + quad * 8;
            stp[i] = 64;
        }
        ldo[i] = u * 512;
    }

    f32x4 o[4];
#pragma unroll
    for (int dt = 0; dt < 4; dt++) o[dt] = (f32x4){0.f, 0.f, 0.f, 0.f};
    float psum = 0.f;                    // per-lane partial sum of 2^s

    // prologue: stage tile 0 (buf0) and, if present, tile 1 (buf1)
#pragma unroll
    for (int i = 0; i < 4; i++) { gload16(gp[i], &SMEM[ldo[i]]); gp[i] += stp[i]; }
    if (strip >= 1) {
#pragma unroll
        for (int i = 0; i < 4; i++) { gload16(gp[i], &SMEM[8192 + ldo[i]]); gp[i] += stp[i]; }
    }

    for (int it = 0; it <= strip; ++it) {
        short* Ks = &SMEM[(it % 3) * 8192];
        short* Vs = Ks + 4096;

        if (it + 2 <= strip) {           // stage tile it+2 into buf (it+2)%3
            short* nb = &SMEM[((it + 2) % 3) * 8192];
#pragma unroll
            for (int i = 0; i < 4; i++) { gload16(gp[i], nb + ldo[i]); gp[i] += stp[i]; }
            asm volatile("s_waitcnt vmcnt(8)" ::: "memory");   // tile(it) landed
        } else if (it + 1 <= strip) {
            asm volatile("s_waitcnt vmcnt(4)" ::: "memory");
        } else {
            asm volatile("s_waitcnt vmcnt(0)" ::: "memory");
        }
        __builtin_amdgcn_s_barrier();    // all waves' tile(it) visible,
                                         // prev compute done (end barrier)
        const int s0 = it * 64;
        f32x4 sv[4];
        __builtin_amdgcn_s_setprio(1);
#pragma unroll
        for (int t = 0; t < 4; t++) {
            sv[t] = (f32x4){0.f, 0.f, 0.f, 0.f};
            short8 k0 = *(const short8*)&Ks[(t * 2) * 512 + lane * 8];
            short8 k1 = *(const short8*)&Ks[(t * 2 + 1) * 512 + lane * 8];
            sv[t] = __builtin_amdgcn_mfma_f32_16x16x32_bf16(k0, bq0, sv[t], 0, 0, 0);
            sv[t] = __builtin_amdgcn_mfma_f32_16x16x32_bf16(k1, bq1, sv[t], 0, 0, 0);
        }
        __builtin_amdgcn_s_setprio(0);

        float p[16];
        if (it == strip) {
#pragma unroll
            for (int t = 0; t < 4; t++)
#pragma unroll
                for (int r = 0; r < 4; r++) {
                    int key = s0 + t * 16 + quad * 4 + r;
                    p[t * 4 + r] = (key <= qr) ? EXP2F(sv[t][r]) : 0.f;
                }
        } else {
#pragma unroll
            for (int t = 0; t < 4; t++)
#pragma unroll
                for (int r = 0; r < 4; r++)
                    p[t * 4 + r] = EXP2F(sv[t][r]);
        }
#pragma unroll
        for (int i = 0; i < 16; i++) psum += p[i];

#pragma unroll
        for (int t = 0; t < 4; t++) {
            uint2 u2;
            u2.x = pk2(p[t * 4],     p[t * 4 + 1]);
            u2.y = pk2(p[t * 4 + 2], p[t * 4 + 3]);
            *(uint2*)&Pw[l15 * 72 + t * 16 + quad * 4] = u2;
        }
        short8 bp0 = *(const short8*)&Pw[l15 * 72 + quad * 8];
        short8 bp1 = *(const short8*)&Pw[l15 * 72 + 32 + quad * 8];

        __builtin_amdgcn_s_setprio(1);
#pragma unroll
        for (int dt = 0; dt < 4; dt++) {
            short8 av0 = *(const short8*)&Vs[(dt * 2) * 512 + lane * 8];
            short8 av1 = *(const short8*)&Vs[(dt * 2 + 1) * 512 + lane * 8];
            o[dt] = __builtin_amdgcn_mfma_f32_16x16x32_bf16(av0, bp0, o[dt], 0, 0, 0);
            o[dt] = __builtin_amdgcn_mfma_f32_16x16x32_bf16(av1, bp1, o[dt], 0, 0, 0);
        }
        __builtin_amdgcn_s_setprio(0);
        __builtin_amdgcn_s_barrier();    // all reads of buf(it%3) done before
                                         // iter it+1 stages into it
    }

    float lrow = psum + __shfl_xor(psum, 16);
    lrow += __shfl_xor(lrow, 32);
    const float inv = 1.f / lrow;

    const size_t obase = (size_t)(b * SEQ + qr) * HDIM + head * DHEAD;
#pragma unroll
    for (int dt = 0; dt < 4; dt++) {
        uint2 u2;
        u2.x = pk2(o[dt][0] * inv, o[dt][1] * inv);
        u2.y = pk2(o[dt][2] * inv, o[dt][3] * inv);
        *(uint2*)&Ab[obase + dt * 16 + quad * 4] = u2;
    }
}

// ---------------------------------------------------------------------------
// O projection, TRIPLE-buffered 2-ahead (same fix): out[4096x1024] fp32 =
// Ab * WoT^T + bo. 64x128 tile, grid (8,64) = 512 blocks. LDS 3x12 = 36 KB.
// ONLY writer of d_out (which held WT scratch until now).
// ---------------------------------------------------------------------------
__global__ __launch_bounds__(256) void gemm_o(const short* __restrict__ A,
        const short* __restrict__ Bt, const float* __restrict__ bo,
        float* __restrict__ Out)
{
    __shared__ short SM[3 * 6144];   // [buf][As 2048 | Bs 4096 shorts]
    const int tid = threadIdx.x, lane = tid & 63, w = tid >> 6;
    const int quad = lane >> 4, l15 = lane & 15;
    const int m0 = blockIdx.y * 64, n0 = blockIdx.x * 128;
    const int wr = w >> 1, wc = w & 1;

    // staging: 12 chunks (4 A + 8 B), 3 per wave
    const short* gsrc[3];
    short* ldst[3];
#pragma unroll
    for (int i = 0; i < 3; i++) {
        int u = w * 3 + i;
        if (u < 4) {
            gsrc[i] = A + (size_t)(m0 + u * 16 + l15) * HDIM + quad * 8;
            ldst[i] = &SM[u * 512];
        } else {
            int v = u - 4;
            gsrc[i] = Bt + (size_t)(n0 + v * 16 + l15) * HDIM + quad * 8;
            ldst[i] = &SM[2048 + v * 512];
        }
    }

    f32x4 acc[2][4];
#pragma unroll
    for (int i = 0; i < 2; i++)
#pragma unroll
        for (int j = 0; j < 4; j++) acc[i][j] = (f32x4){0.f, 0.f, 0.f, 0.f};

    // prologue: stage tiles 0 and 1
#pragma unroll
    for (int i = 0; i < 3; i++) { gload16(gsrc[i], ldst[i]); gsrc[i] += 32; }
#pragma unroll
    for (int i = 0; i < 3; i++) { gload16(gsrc[i], ldst[i] + 6144); gsrc[i] += 32; }

    for (int kk = 0; kk < 32; ++kk) {
        if (kk < 30) {
            const int nb = ((kk + 2) % 3) * 6144;
#pragma unroll
            for (int i = 0; i < 3; i++) { gload16(gsrc[i], ldst[i] + nb); gsrc[i] += 32; }
            asm volatile("s_waitcnt vmcnt(6)" ::: "memory");   // tile(kk) landed
        } else if (kk == 30) {
            asm volatile("s_waitcnt vmcnt(3)" ::: "memory");
        } else {
            asm volatile("s_waitcnt vmcnt(0)" ::: "memory");
        }
        __builtin_amdgcn_s_barrier();

        const short* Asb = &SM[(kk % 3) * 6144];
        const short* Bsb = Asb + 2048;
        short8 af[2], bfr[4];
#pragma unroll
        for (int mi = 0; mi < 2; mi++)
            af[mi] = *(const short8*)&Asb[(wr * 2 + mi) * 512 + lane * 8];
#pragma unroll
        for (int ni = 0; ni < 4; ni++)
            bfr[ni] = *(const short8*)&Bsb[(wc * 4 + ni) * 512 + lane * 8];
#pragma unroll
        for (int mi = 0; mi < 2; mi++)
#pragma unroll
            for (int ni = 0; ni < 4; ni++)
                acc[mi][ni] = __builtin_amdgcn_mfma_f32_16x16x32_bf16(
                                  af[mi], bfr[ni], acc[mi][ni], 0, 0, 0);
        __builtin_amdgcn_s_barrier();
    }

#pragma unroll
    for (int mi = 0; mi < 2; mi++) {
        int mB = m0 + (wr * 2 + mi) * 16 + quad * 4;
#pragma unroll
        for (int ni = 0; ni < 4; ni++) {
            int n = n0 + (wc * 4 + ni) * 16 + l15;
            float bb = bo[n];
#pragma unroll
            for (int r = 0; r < 4; r++)
                Out[(size_t)(mB + r) * HDIM + n] = acc[mi][ni][r] + bb;
        }
    }
}

// ---------------------------------------------------------------------------
extern "C" void kernel_launch(void* const* d_in, const int* in_sizes, int n_in,
                              void* d_out, int out_size, void* d_ws, size_t ws_size,
                              hipStream_t stream)
{
    const float* src = (const float*)d_in[0];
    const float* Wq = (const float*)d_in[2];
    const float* bq = (const float*)d_in[3];
    const float* Wk = (const float*)d_in[4];
    const float* bk = (const float*)d_in[5];
    const float* Wv = (const float*)d_in[6];
    const float* bv = (const float*)d_in[7];
    const float* Wo = (const float*)d_in[8];
    const float* bo = (const float*)d_in[9];
    float* out = (float*)d_out;

    // ws (34 MB): [Sb 8][Qb 8][Kb 8][Vt 8][WoT slot 2]
    // Merged transposed QKV weights WT (3072x1024 bf16 = 6 MB) live in d_out
    // (16 MB fp32), which is dead scratch until gemm_o fully overwrites it.
    short* Sb   = (short*)d_ws;
    short* Qb   = Sb + (size_t)MROWS * HDIM;
    short* Kb   = Qb + (size_t)MROWS * HDIM;
    short* Vt   = Kb + (size_t)MROWS * HDIM;
    short* WoT  = Vt + (size_t)MROWS * HDIM;   // 2 MB slot
    short* WT   = (short*)d_out;               // 6 MB scratch in out buffer
    short* Ab   = Qb;                          // attention output over Q

    prep1<<<dim3(4096 + 1024), dim3(256), 0, stream>>>(src, Wq, Wk, Wv, Wo, Sb, WT, WoT);

    gemm_qkv<<<dim3(24, 16), dim3(512), 0, stream>>>(Sb, WT, bq, bk, bv, Qb, Kb, Vt);

    attn_mfma<<<dim3(1024), dim3(256), 0, stream>>>(Qb, Kb, Vt, Ab);

    gemm_o<<<dim3(8, 64), dim3(256), 0, stream>>>(Ab, WoT, bo, out);
}

// Round 8
// 206.715 us; speedup vs baseline: 1.0270x; 1.0270x over previous
//
#include <hip/hip_runtime.h>
#include <hip/hip_bf16.h>

typedef __hip_bfloat16 bf16;
typedef __attribute__((ext_vector_type(8))) short short8;   // 8 bf16 = 4 VGPRs
typedef __attribute__((ext_vector_type(4))) float f32x4;

#define BATCH 2
#define SEQ   2048
#define HDIM  1024
#define NHEAD 16
#define DHEAD 64
#define MROWS (BATCH*SEQ)   // 4096

// scale folded into Q: (1/sqrt(64)) * log2(e)  -> softmax done in 2^x domain
#define QSCALE 0.18033688f
#define EXP2F(x) __builtin_amdgcn_exp2f(x)

static __device__ __forceinline__ short f2bs(float x) {
    __hip_bfloat16 h = (__hip_bfloat16)x;   // RNE convert
    return *reinterpret_cast<short*>(&h);
}
static __device__ __forceinline__ unsigned int pk2(float a, float b) {
    __hip_bfloat162 h = __float22bfloat162_rn(make_float2(a, b));
    return *reinterpret_cast<unsigned int*>(&h);   // v_cvt_pk; low short = a
}

// async global->LDS, 16B per lane; lane l lands at base + l*16.
static __device__ __forceinline__ void gload16(const void* g, void* l) {
    __builtin_amdgcn_global_load_lds(
        (const __attribute__((address_space(1))) unsigned int*)g,
        (__attribute__((address_space(3))) unsigned int*)l, 16, 0, 0);
}

// ---------------------------------------------------------------------------
// prep1: blocks 0..4095 convert src fp32->bf16 into Sb; blocks 4096..5119
// transpose all four weights: Wq,Wk,Wv into WT rows wsel*1024+n (WT lives in
// d_out scratch, dead until gemm_o overwrites it), Wo into WoT (slot).
// ---------------------------------------------------------------------------
__global__ __launch_bounds__(256) void prep1(const float* __restrict__ src,
        const float* __restrict__ Wq, const float* __restrict__ Wk,
        const float* __restrict__ Wv, const float* __restrict__ Wo,
        short* __restrict__ Sb, short* __restrict__ WT,
        short* __restrict__ WoT)
{
    __shared__ float t[64][65];
    const int bx = blockIdx.x, tid = threadIdx.x;
    if (bx < 4096) {                       // cvt: 4096*256 float4 = 4M elems
        int i = bx * 256 + tid;
        float4 v = ((const float4*)src)[i];
        ushort4 o;
        o.x = (unsigned short)f2bs(v.x);
        o.y = (unsigned short)f2bs(v.y);
        o.z = (unsigned short)f2bs(v.z);
        o.w = (unsigned short)f2bs(v.w);
        ((ushort4*)Sb)[i] = o;
        return;
    }
    const int tb = bx - 4096;              // [0, 1024)
    const int wsel = tb >> 8;              // 0=Wq 1=Wk 2=Wv 3=Wo
    const float* W = (wsel == 0) ? Wq : (wsel == 1) ? Wk : (wsel == 2) ? Wv : Wo;
    short* dst = (wsel < 3) ? WT : WoT;
    const int roff = (wsel < 3) ? wsel * 1024 : 0;
    const int t8 = tb & 255;
    const int n0 = (t8 & 15) * 64, k0 = (t8 >> 4) * 64;
#pragma unroll
    for (int i = 0; i < 16; i++) {
        int idx = tid + i * 256, r = idx >> 6, c = idx & 63;
        t[r][c] = W[(size_t)(k0 + r) * HDIM + n0 + c];
    }
    __syncthreads();
#pragma unroll
    for (int i = 0; i < 16; i++) {
        int idx = tid + i * 256, c = idx >> 6, r = idx & 63;
        dst[(size_t)(roff + n0 + c) * HDIM + k0 + r] = f2bs(t[r][c]);
    }
}

// ---------------------------------------------------------------------------
// Fused Q|K|V GEMM — 8-phase 256x256 template (m201 port). Evidence R1-R7:
// the 2-barrier K-loop has a ~1.8-2.4us per-iteration latency floor invariant
// to prefetch depth/BK/tile; the m201 8-phase schedule breaks it (~820cy per
// 16-MFMA phase). Geometry: 512 thr / 8 waves (4M x 2N), BK=64, grid (12,16),
// 1 block/CU, LDS 128 KB dbuf, fragment-major chunks (bank-conflict-free by
// construction -> no swizzle needed). Per K-tile t: 4 phases; phase p:
//   {ds_read bf pair (p==0: + all af) | stage group p of tile t+1 (2 gloads)
//    | vmcnt(4)@p1, vmcnt(2)@p3 ONLY | barrier | lgkmcnt(0) | setprio(1)
//    | 16 MFMA | setprio(0) | barrier}
// Stage groups: g0=A rows 0-127, g1=A rows 128-255, g2=B(ni0-3), g3=B(ni4-7).
// Wait accounting (per-thread, 2 loads/group): after p1-issue outstanding =
// {tBh1, t+1Ah0, t+1Ah1}=6 -> vmcnt(4) retires tBh1 (needed p2). After
// p3-issue = {t+1 Ah0,Ah1,Bh0,Bh1}=8 -> vmcnt(2) retires Ah0,Ah1,Bh0 (needed
// t+1 p0). Tail t=15: vmcnt(0)@p1. MFMA k-order per acc unchanged -> bit-
// identical output. Region by bx>>2: 0=Q, 1=K, 2=V (transposed store).
// ---------------------------------------------------------------------------
__global__ __launch_bounds__(512, 2) void gemm_qkv(const short* __restrict__ A,
        const short* __restrict__ Bt,
        const float* __restrict__ bq, const float* __restrict__ bk,
        const float* __restrict__ bv,
        short* __restrict__ Qout, short* __restrict__ Kout,
        short* __restrict__ Vtout)
{
    __shared__ short SM[2][32768];   // [buf][A 16384 | B 16384] = 128 KB
    const int tid = threadIdx.x, lane = tid & 63, w = tid >> 6;   // w 0..7
    const int quad = lane >> 4, l15 = lane & 15;
    const int m0 = blockIdx.y * 256, n0 = blockIdx.x * 256;
    const int wr = w >> 1, wc = w & 1;     // 4M x 2N wave grid

    // staging: 64 chunks/K-tile (chunk = 16 rows x 32 k = 1 KB, one gload16
    // per wave); 4 groups x 16 chunks; per wave 2 chunks per group.
    const short* gp[4][2];
    int lo[4][2];
#pragma unroll
    for (int g = 0; g < 4; g++)
#pragma unroll
        for (int i = 0; i < 2; i++) {
            if (g < 2) {
                int u = g * 16 + w * 2 + i;          // A chunk 0..31
                gp[g][i] = A + (size_t)(m0 + (u >> 1) * 16 + l15) * HDIM
                             + (u & 1) * 32 + quad * 8;
                lo[g][i] = u * 512;
            } else {
                int j = w * 2 + i;                   // 0..15
                int v = (g == 2 ? 0 : 8) + j + (j >= 8 ? 8 : 0);  // B chunk
                gp[g][i] = Bt + (size_t)(n0 + (v >> 1) * 16 + l15) * HDIM
                              + (v & 1) * 32 + quad * 8;
                lo[g][i] = 16384 + v * 512;
            }
        }

    f32x4 acc[4][8];
#pragma unroll
    for (int i = 0; i < 4; i++)
#pragma unroll
        for (int j = 0; j < 8; j++) acc[i][j] = (f32x4){0.f, 0.f, 0.f, 0.f};

    // prologue: stage tile 0 (groups in order g0,g1,g2,g3)
#pragma unroll
    for (int g = 0; g < 4; g++)
#pragma unroll
        for (int i = 0; i < 2; i++) { gload16(gp[g][i], &SM[0][lo[g][i]]); gp[g][i] += 64; }
    asm volatile("s_waitcnt vmcnt(2)" ::: "memory");   // Ah0,Ah1,Bh0 landed
    __builtin_amdgcn_s_barrier();

    short8 af[4][2];
    for (int t = 0; t < 16; ++t) {
        const short* Tb = SM[t & 1];
        short* Sn = SM[(t + 1) & 1];
#pragma unroll
        for (int p = 0; p < 4; ++p) {
            // ds_reads for this phase (data readiness ensured by the waits
            // of the PREVIOUS phases — see accounting in header comment)
            if (p == 0) {
#pragma unroll
                for (int mi = 0; mi < 4; mi++)
#pragma unroll
                    for (int kh = 0; kh < 2; kh++)
                        af[mi][kh] = *(const short8*)
                            &Tb[((wr * 4 + mi) * 2 + kh) * 512 + lane * 8];
            }
            short8 bfp[2][2];
#pragma unroll
            for (int n2 = 0; n2 < 2; n2++)
#pragma unroll
                for (int kh = 0; kh < 2; kh++)
                    bfp[n2][kh] = *(const short8*)
                        &Tb[16384 + ((wc * 8 + p * 2 + n2) * 2 + kh) * 512 + lane * 8];

            // stage group p of tile t+1 into the other buffer
            if (t < 15) {
                gload16(gp[p][0], Sn + lo[p][0]); gp[p][0] += 64;
                gload16(gp[p][1], Sn + lo[p][1]); gp[p][1] += 64;
                if (p == 1) asm volatile("s_waitcnt vmcnt(4)" ::: "memory");
                if (p == 3) asm volatile("s_waitcnt vmcnt(2)" ::: "memory");
            } else {
                if (p == 1) asm volatile("s_waitcnt vmcnt(0)" ::: "memory");
            }
            __builtin_amdgcn_s_barrier();
            asm volatile("s_waitcnt lgkmcnt(0)" ::: "memory");
            __builtin_amdgcn_s_setprio(1);
#pragma unroll
            for (int n2 = 0; n2 < 2; n2++)
#pragma unroll
                for (int mi = 0; mi < 4; mi++)
#pragma unroll
                    for (int kh = 0; kh < 2; kh++)
                        acc[mi][p * 2 + n2] = __builtin_amdgcn_mfma_f32_16x16x32_bf16(
                            af[mi][kh], bfp[n2][kh], acc[mi][p * 2 + n2], 0, 0, 0);
            __builtin_amdgcn_s_setprio(0);
            __builtin_amdgcn_s_barrier();
        }
    }

    const int region = blockIdx.x >> 2;          // 0=Q, 1=K, 2=V
    if (region < 2) {
        const float* bias = region ? bk : bq;
        const float oscale = region ? 1.0f : QSCALE;
        short* C = region ? Kout : Qout;
#pragma unroll
        for (int mi = 0; mi < 4; mi++) {
            int mB = m0 + wr * 64 + mi * 16 + quad * 4;
#pragma unroll
            for (int ni = 0; ni < 8; ni++) {
                int nl = (n0 + (wc * 8 + ni) * 16 + l15) & 1023;
                float bb = bias[nl];
#pragma unroll
                for (int r = 0; r < 4; r++)
                    C[(size_t)(mB + r) * HDIM + nl] =
                        f2bs((acc[mi][ni][r] + bb) * oscale);
            }
        }
    } else {                                     // V: transposed store
#pragma unroll
        for (int mi = 0; mi < 4; mi++) {
            int mB = m0 + wr * 64 + mi * 16 + quad * 4;
            int bb = mB >> 11, tt = mB & 2047;
#pragma unroll
            for (int ni = 0; ni < 8; ni++) {
                int n = n0 + (wc * 8 + ni) * 16 + l15;   // 2048..3071
                int h = (n >> 6) & 15, d = n & 63;
                float bvv = bv[n & 1023];
                size_t base = ((size_t)((bb * NHEAD + h) * DHEAD + d)) * SEQ + tt;
                ushort4 pk;
                pk.x = (unsigned short)f2bs(acc[mi][ni][0] + bvv);
                pk.y = (unsigned short)f2bs(acc[mi][ni][1] + bvv);
                pk.z = (unsigned short)f2bs(acc[mi][ni][2] + bvv);
                pk.w = (unsigned short)f2bs(acc[mi][ni][3] + bvv);
                *(ushort4*)(Vtout + base) = pk;
            }
        }
    }
}

// ---------------------------------------------------------------------------
// MFMA causal flash attention, TRIPLE-buffered K/V staging with 2-ahead
// prefetch (R7, passed): stage tile it+2 at iter it; wait vmcnt(8), tails
// vmcnt(4)/vmcnt(0). s_setprio(1) around MFMA clusters. Fixed-max softmax
// (p = 2^s). LDS: 3 x 16 KB K|V buffers + 9 KB P = 57 KB.
// ---------------------------------------------------------------------------
__global__ __launch_bounds__(256) void attn_mfma(const short* __restrict__ Qb,
        const short* __restrict__ Kb, const short* __restrict__ Vt,
        short* __restrict__ Ab)
{
    __shared__ short SMEM[29184];        // [3][8192] K|V tbuf | Ps 4x1152
    const int tid = threadIdx.x, lane = tid & 63, w = tid >> 6;
    const int quad = lane >> 4, l15 = lane & 15;
    const int L = blockIdx.x;

    // xcd = L%8 fixed per (b,head); strip = 31-(L>>5) (longest first)
    const int pair = (L & 7) + 8 * ((L >> 3) & 3);   // 0..31
    const int strip = 31 - (L >> 5);                 // 0..31
    const int b = pair >> 4, head = pair & 15;

    const short* Kbh = Kb + (size_t)b * SEQ * HDIM + head * DHEAD;
    const short* Vth = Vt + (size_t)(b * NHEAD + head) * DHEAD * SEQ;
    short* Pw = SMEM + 24576 + w * 1152;

    const int qbase = strip * 64;
    const int qr = qbase + w * 16 + l15;

    const short* qptr = Qb + (size_t)(b * SEQ + qr) * HDIM + head * DHEAD + quad * 8;
    short8 bq0 = *(const short8*)qptr;
    short8 bq1 = *(const short8*)(qptr + 32);

    // staging pointers: 4 chunks per wave (u<8: K, u>=8: V), incremented
    const short* gp[4];
    int stp[4], ldo[4];
#pragma unroll
    for (int i = 0; i < 4; i++) {
        int u = w * 4 + i;
        if (u < 8) {
            int t = u >> 1, h = u & 1;
            gp[i] = Kbh + (size_t)(t * 16 + l15) * HDIM + h * 32 + quad * 8;
            stp[i] = 64 * HDIM;
        } else {
            int c = u - 8, dt = c >> 1, kh = c & 1;
            gp[i] = Vth + (size_t)(dt * 16 + l15) * SEQ + kh * 32 + quad * 8;
            stp[i] = 64;
        }
        ldo[i] = u * 512;
    }

    f32x4 o[4];
#pragma unroll
    for (int dt = 0; dt < 4; dt++) o[dt] = (f32x4){0.f, 0.f, 0.f, 0.f};
    float psum = 0.f;                    // per-lane partial sum of 2^s

    // prologue: stage tile 0 (buf0) and, if present, tile 1 (buf1)
#pragma unroll
    for (int i = 0; i < 4; i++) { gload16(gp[i], &SMEM[ldo[i]]); gp[i] += stp[i]; }
    if (strip >= 1) {
#pragma unroll
        for (int i = 0; i < 4; i++) { gload16(gp[i], &SMEM[8192 + ldo[i]]); gp[i] += stp[i]; }
    }

    for (int it = 0; it <= strip; ++it) {
        short* Ks = &SMEM[(it % 3) * 8192];
        short* Vs = Ks + 4096;

        if (it + 2 <= strip) {           // stage tile it+2 into buf (it+2)%3
            short* nb = &SMEM[((it + 2) % 3) * 8192];
#pragma unroll
            for (int i = 0; i < 4; i++) { gload16(gp[i], nb + ldo[i]); gp[i] += stp[i]; }
            asm volatile("s_waitcnt vmcnt(8)" ::: "memory");   // tile(it) landed
        } else if (it + 1 <= strip) {
            asm volatile("s_waitcnt vmcnt(4)" ::: "memory");
        } else {
            asm volatile("s_waitcnt vmcnt(0)" ::: "memory");
        }
        __builtin_amdgcn_s_barrier();    // all waves' tile(it) visible,
                                         // prev compute done (end barrier)
        const int s0 = it * 64;
        f32x4 sv[4];
        __builtin_amdgcn_s_setprio(1);
#pragma unroll
        for (int t = 0; t < 4; t++) {
            sv[t] = (f32x4){0.f, 0.f, 0.f, 0.f};
            short8 k0 = *(const short8*)&Ks[(t * 2) * 512 + lane * 8];
            short8 k1 = *(const short8*)&Ks[(t * 2 + 1) * 512 + lane * 8];
            sv[t] = __builtin_amdgcn_mfma_f32_16x16x32_bf16(k0, bq0, sv[t], 0, 0, 0);
            sv[t] = __builtin_amdgcn_mfma_f32_16x16x32_bf16(k1, bq1, sv[t], 0, 0, 0);
        }
        __builtin_amdgcn_s_setprio(0);

        float p[16];
        if (it == strip) {
#pragma unroll
            for (int t = 0; t < 4; t++)
#pragma unroll
                for (int r = 0; r < 4; r++) {
                    int key = s0 + t * 16 + quad * 4 + r;
                    p[t * 4 + r] = (key <= qr) ? EXP2F(sv[t][r]) : 0.f;
                }
        } else {
#pragma unroll
            for (int t = 0; t < 4; t++)
#pragma unroll
                for (int r = 0; r < 4; r++)
                    p[t * 4 + r] = EXP2F(sv[t][r]);
        }
#pragma unroll
        for (int i = 0; i < 16; i++) psum += p[i];

#pragma unroll
        for (int t = 0; t < 4; t++) {
            uint2 u2;
            u2.x = pk2(p[t * 4],     p[t * 4 + 1]);
            u2.y = pk2(p[t * 4 + 2], p[t * 4 + 3]);
            *(uint2*)&Pw[l15 * 72 + t * 16 + quad * 4] = u2;
        }
        short8 bp0 = *(const short8*)&Pw[l15 * 72 + quad * 8];
        short8 bp1 = *(const short8*)&Pw[l15 * 72 + 32 + quad * 8];

        __builtin_amdgcn_s_setprio(1);
#pragma unroll
        for (int dt = 0; dt < 4; dt++) {
            short8 av0 = *(const short8*)&Vs[(dt * 2) * 512 + lane * 8];
            short8 av1 = *(const short8*)&Vs[(dt * 2 + 1) * 512 + lane * 8];
            o[dt] = __builtin_amdgcn_mfma_f32_16x16x32_bf16(av0, bp0, o[dt], 0, 0, 0);
            o[dt] = __builtin_amdgcn_mfma_f32_16x16x32_bf16(av1, bp1, o[dt], 0, 0, 0);
        }
        __builtin_amdgcn_s_setprio(0);
        __builtin_amdgcn_s_barrier();    // all reads of buf(it%3) done before
                                         // iter it+1 stages into it
    }

    float lrow = psum + __shfl_xor(psum, 16);
    lrow += __shfl_xor(lrow, 32);
    const float inv = 1.f / lrow;

    const size_t obase = (size_t)(b * SEQ + qr) * HDIM + head * DHEAD;
#pragma unroll
    for (int dt = 0; dt < 4; dt++) {
        uint2 u2;
        u2.x = pk2(o[dt][0] * inv, o[dt][1] * inv);
        u2.y = pk2(o[dt][2] * inv, o[dt][3] * inv);
        *(uint2*)&Ab[obase + dt * 16 + quad * 4] = u2;
    }
}

// ---------------------------------------------------------------------------
// O projection, TRIPLE-buffered 2-ahead (R7, passed): out[4096x1024] fp32 =
// Ab * WoT^T + bo. 64x128 tile, grid (8,64) = 512 blocks. LDS 3x12 = 36 KB.
// ONLY writer of d_out (which held WT scratch until now).
// ---------------------------------------------------------------------------
__global__ __launch_bounds__(256) void gemm_o(const short* __restrict__ A,
        const short* __restrict__ Bt, const float* __restrict__ bo,
        float* __restrict__ Out)
{
    __shared__ short SM[3 * 6144];   // [buf][As 2048 | Bs 4096 shorts]
    const int tid = threadIdx.x, lane = tid & 63, w = tid >> 6;
    const int quad = lane >> 4, l15 = lane & 15;
    const int m0 = blockIdx.y * 64, n0 = blockIdx.x * 128;
    const int wr = w >> 1, wc = w & 1;

    // staging: 12 chunks (4 A + 8 B), 3 per wave
    const short* gsrc[3];
    short* ldst[3];
#pragma unroll
    for (int i = 0; i < 3; i++) {
        int u = w * 3 + i;
        if (u < 4) {
            gsrc[i] = A + (size_t)(m0 + u * 16 + l15) * HDIM + quad * 8;
            ldst[i] = &SM[u * 512];
        } else {
            int v = u - 4;
            gsrc[i] = Bt + (size_t)(n0 + v * 16 + l15) * HDIM + quad * 8;
            ldst[i] = &SM[2048 + v * 512];
        }
    }

    f32x4 acc[2][4];
#pragma unroll
    for (int i = 0; i < 2; i++)
#pragma unroll
        for (int j = 0; j < 4; j++) acc[i][j] = (f32x4){0.f, 0.f, 0.f, 0.f};

    // prologue: stage tiles 0 and 1
#pragma unroll
    for (int i = 0; i < 3; i++) { gload16(gsrc[i], ldst[i]); gsrc[i] += 32; }
#pragma unroll
    for (int i = 0; i < 3; i++) { gload16(gsrc[i], ldst[i] + 6144); gsrc[i] += 32; }

    for (int kk = 0; kk < 32; ++kk) {
        if (kk < 30) {
            const int nb = ((kk + 2) % 3) * 6144;
#pragma unroll
            for (int i = 0; i < 3; i++) { gload16(gsrc[i], ldst[i] + nb); gsrc[i] += 32; }
            asm volatile("s_waitcnt vmcnt(6)" ::: "memory");   // tile(kk) landed
        } else if (kk == 30) {
            asm volatile("s_waitcnt vmcnt(3)" ::: "memory");
        } else {
            asm volatile("s_waitcnt vmcnt(0)" ::: "memory");
        }
        __builtin_amdgcn_s_barrier();

        const short* Asb = &SM[(kk % 3) * 6144];
        const short* Bsb = Asb + 2048;
        short8 af[2], bfr[4];
#pragma unroll
        for (int mi = 0; mi < 2; mi++)
            af[mi] = *(const short8*)&Asb[(wr * 2 + mi) * 512 + lane * 8];
#pragma unroll
        for (int ni = 0; ni < 4; ni++)
            bfr[ni] = *(const short8*)&Bsb[(wc * 4 + ni) * 512 + lane * 8];
#pragma unroll
        for (int mi = 0; mi < 2; mi++)
#pragma unroll
            for (int ni = 0; ni < 4; ni++)
                acc[mi][ni] = __builtin_amdgcn_mfma_f32_16x16x32_bf16(
                                  af[mi], bfr[ni], acc[mi][ni], 0, 0, 0);
        __builtin_amdgcn_s_barrier();
    }

#pragma unroll
    for (int mi = 0; mi < 2; mi++) {
        int mB = m0 + (wr * 2 + mi) * 16 + quad * 4;
#pragma unroll
        for (int ni = 0; ni < 4; ni++) {
            int n = n0 + (wc * 4 + ni) * 16 + l15;
            float bb = bo[n];
#pragma unroll
            for (int r = 0; r < 4; r++)
                Out[(size_t)(mB + r) * HDIM + n] = acc[mi][ni][r] + bb;
        }
    }
}

// ---------------------------------------------------------------------------
extern "C" void kernel_launch(void* const* d_in, const int* in_sizes, int n_in,
                              void* d_out, int out_size, void* d_ws, size_t ws_size,
                              hipStream_t stream)
{
    const float* src = (const float*)d_in[0];
    const float* Wq = (const float*)d_in[2];
    const float* bq = (const float*)d_in[3];
    const float* Wk = (const float*)d_in[4];
    const float* bk = (const float*)d_in[5];
    const float* Wv = (const float*)d_in[6];
    const float* bv = (const float*)d_in[7];
    const float* Wo = (const float*)d_in[8];
    const float* bo = (const float*)d_in[9];
    float* out = (float*)d_out;

    // ws (34 MB): [Sb 8][Qb 8][Kb 8][Vt 8][WoT slot 2]
    // Merged transposed QKV weights WT (3072x1024 bf16 = 6 MB) live in d_out
    // (16 MB fp32), which is dead scratch until gemm_o fully overwrites it.
    short* Sb   = (short*)d_ws;
    short* Qb   = Sb + (size_t)MROWS * HDIM;
    short* Kb   = Qb + (size_t)MROWS * HDIM;
    short* Vt   = Kb + (size_t)MROWS * HDIM;
    short* WoT  = Vt + (size_t)MROWS * HDIM;   // 2 MB slot
    short* WT   = (short*)d_out;               // 6 MB scratch in out buffer
    short* Ab   = Qb;                          // attention output over Q

    prep1<<<dim3(4096 + 1024), dim3(256), 0, stream>>>(src, Wq, Wk, Wv, Wo, Sb, WT, WoT);

    gemm_qkv<<<dim3(12, 16), dim3(512), 0, stream>>>(Sb, WT, bq, bk, bv, Qb, Kb, Vt);

    attn_mfma<<<dim3(1024), dim3(256), 0, stream>>>(Qb, Kb, Vt, Ab);

    gemm_o<<<dim3(8, 64), dim3(256), 0, stream>>>(Ab, WoT, bo, out);
}

// Round 9
// 203.730 us; speedup vs baseline: 1.0421x; 1.0147x over previous
//
#include <hip/hip_runtime.h>
#include <hip/hip_bf16.h>

typedef __hip_bfloat16 bf16;
typedef __attribute__((ext_vector_type(8))) short short8;   // 8 bf16 = 4 VGPRs
typedef __attribute__((ext_vector_type(4))) float f32x4;

#define BATCH 2
#define SEQ   2048
#define HDIM  1024
#define NHEAD 16
#define DHEAD 64
#define MROWS (BATCH*SEQ)   // 4096

// scale folded into Q: (1/sqrt(64)) * log2(e)  -> softmax done in 2^x domain
#define QSCALE 0.18033688f
#define EXP2F(x) __builtin_amdgcn_exp2f(x)

static __device__ __forceinline__ short f2bs(float x) {
    __hip_bfloat16 h = (__hip_bfloat16)x;   // RNE convert
    return *reinterpret_cast<short*>(&h);
}
static __device__ __forceinline__ unsigned int pk2(float a, float b) {
    __hip_bfloat162 h = __float22bfloat162_rn(make_float2(a, b));
    return *reinterpret_cast<unsigned int*>(&h);   // v_cvt_pk; low short = a
}

// async global->LDS, 16B per lane; lane l lands at base + l*16.
static __device__ __forceinline__ void gload16(const void* g, void* l) {
    __builtin_amdgcn_global_load_lds(
        (const __attribute__((address_space(1))) unsigned int*)g,
        (__attribute__((address_space(3))) unsigned int*)l, 16, 0, 0);
}

// ---------------------------------------------------------------------------
// prep1: blocks 0..4095 convert src fp32->bf16 into Sb; blocks 4096..5119
// transpose all four weights: Wq,Wk,Wv into WT rows wsel*1024+n (WT lives in
// d_out scratch, dead until gemm_o overwrites it), Wo into WoT (slot).
// ---------------------------------------------------------------------------
__global__ __launch_bounds__(256) void prep1(const float* __restrict__ src,
        const float* __restrict__ Wq, const float* __restrict__ Wk,
        const float* __restrict__ Wv, const float* __restrict__ Wo,
        short* __restrict__ Sb, short* __restrict__ WT,
        short* __restrict__ WoT)
{
    __shared__ float t[64][65];
    const int bx = blockIdx.x, tid = threadIdx.x;
    if (bx < 4096) {                       // cvt: 4096*256 float4 = 4M elems
        int i = bx * 256 + tid;
        float4 v = ((const float4*)src)[i];
        ushort4 o;
        o.x = (unsigned short)f2bs(v.x);
        o.y = (unsigned short)f2bs(v.y);
        o.z = (unsigned short)f2bs(v.z);
        o.w = (unsigned short)f2bs(v.w);
        ((ushort4*)Sb)[i] = o;
        return;
    }
    const int tb = bx - 4096;              // [0, 1024)
    const int wsel = tb >> 8;              // 0=Wq 1=Wk 2=Wv 3=Wo
    const float* W = (wsel == 0) ? Wq : (wsel == 1) ? Wk : (wsel == 2) ? Wv : Wo;
    short* dst = (wsel < 3) ? WT : WoT;
    const int roff = (wsel < 3) ? wsel * 1024 : 0;
    const int t8 = tb & 255;
    const int n0 = (t8 & 15) * 64, k0 = (t8 >> 4) * 64;
#pragma unroll
    for (int i = 0; i < 16; i++) {
        int idx = tid + i * 256, r = idx >> 6, c = idx & 63;
        t[r][c] = W[(size_t)(k0 + r) * HDIM + n0 + c];
    }
    __syncthreads();
#pragma unroll
    for (int i = 0; i < 16; i++) {
        int idx = tid + i * 256, c = idx >> 6, r = idx & 63;
        dst[(size_t)(roff + n0 + c) * HDIM + k0 + r] = f2bs(t[r][c]);
    }
}

// ---------------------------------------------------------------------------
// Fused Q|K|V GEMM — 8-phase 256x256 template (R8, passed at 48.7us), with
// ONE change: the forced `s_waitcnt lgkmcnt(0)` before the MFMA cluster is
// REMOVED. The ds_reads are compiler-visible, so hipcc inserts fine-grained
// lgkmcnt(N) before each dependent MFMA (guide §5/m97 asm evidence) — MFMAs
// start as their operands arrive instead of draining all 4-12 phase reads.
// Everything else identical to R8 (geometry, staging groups, vmcnt plan).
// ---------------------------------------------------------------------------
__global__ __launch_bounds__(512, 2) void gemm_qkv(const short* __restrict__ A,
        const short* __restrict__ Bt,
        const float* __restrict__ bq, const float* __restrict__ bk,
        const float* __restrict__ bv,
        short* __restrict__ Qout, short* __restrict__ Kout,
        short* __restrict__ Vtout)
{
    __shared__ short SM[2][32768];   // [buf][A 16384 | B 16384] = 128 KB
    const int tid = threadIdx.x, lane = tid & 63, w = tid >> 6;   // w 0..7
    const int quad = lane >> 4, l15 = lane & 15;
    const int m0 = blockIdx.y * 256, n0 = blockIdx.x * 256;
    const int wr = w >> 1, wc = w & 1;     // 4M x 2N wave grid

    // staging: 64 chunks/K-tile (chunk = 16 rows x 32 k = 1 KB, one gload16
    // per wave); 4 groups x 16 chunks; per wave 2 chunks per group.
    const short* gp[4][2];
    int lo[4][2];
#pragma unroll
    for (int g = 0; g < 4; g++)
#pragma unroll
        for (int i = 0; i < 2; i++) {
            if (g < 2) {
                int u = g * 16 + w * 2 + i;          // A chunk 0..31
                gp[g][i] = A + (size_t)(m0 + (u >> 1) * 16 + l15) * HDIM
                             + (u & 1) * 32 + quad * 8;
                lo[g][i] = u * 512;
            } else {
                int j = w * 2 + i;                   // 0..15
                int v = (g == 2 ? 0 : 8) + j + (j >= 8 ? 8 : 0);  // B chunk
                gp[g][i] = Bt + (size_t)(n0 + (v >> 1) * 16 + l15) * HDIM
                              + (v & 1) * 32 + quad * 8;
                lo[g][i] = 16384 + v * 512;
            }
        }

    f32x4 acc[4][8];
#pragma unroll
    for (int i = 0; i < 4; i++)
#pragma unroll
        for (int j = 0; j < 8; j++) acc[i][j] = (f32x4){0.f, 0.f, 0.f, 0.f};

    // prologue: stage tile 0 (groups in order g0,g1,g2,g3)
#pragma unroll
    for (int g = 0; g < 4; g++)
#pragma unroll
        for (int i = 0; i < 2; i++) { gload16(gp[g][i], &SM[0][lo[g][i]]); gp[g][i] += 64; }
    asm volatile("s_waitcnt vmcnt(2)" ::: "memory");   // Ah0,Ah1,Bh0 landed
    __builtin_amdgcn_s_barrier();

    short8 af[4][2];
    for (int t = 0; t < 16; ++t) {
        const short* Tb = SM[t & 1];
        short* Sn = SM[(t + 1) & 1];
#pragma unroll
        for (int p = 0; p < 4; ++p) {
            // ds_reads for this phase (data readiness ensured by the waits
            // of the PREVIOUS phases — see R8 accounting)
            if (p == 0) {
#pragma unroll
                for (int mi = 0; mi < 4; mi++)
#pragma unroll
                    for (int kh = 0; kh < 2; kh++)
                        af[mi][kh] = *(const short8*)
                            &Tb[((wr * 4 + mi) * 2 + kh) * 512 + lane * 8];
            }
            short8 bfp[2][2];
#pragma unroll
            for (int n2 = 0; n2 < 2; n2++)
#pragma unroll
                for (int kh = 0; kh < 2; kh++)
                    bfp[n2][kh] = *(const short8*)
                        &Tb[16384 + ((wc * 8 + p * 2 + n2) * 2 + kh) * 512 + lane * 8];

            // stage group p of tile t+1 into the other buffer
            if (t < 15) {
                gload16(gp[p][0], Sn + lo[p][0]); gp[p][0] += 64;
                gload16(gp[p][1], Sn + lo[p][1]); gp[p][1] += 64;
                if (p == 1) asm volatile("s_waitcnt vmcnt(4)" ::: "memory");
                if (p == 3) asm volatile("s_waitcnt vmcnt(2)" ::: "memory");
            } else {
                if (p == 1) asm volatile("s_waitcnt vmcnt(0)" ::: "memory");
            }
            __builtin_amdgcn_s_barrier();
            // NOTE: no forced lgkmcnt(0) — compiler emits fine-grained
            // lgkmcnt(N) before each MFMA's first operand use.
            __builtin_amdgcn_s_setprio(1);
#pragma unroll
            for (int n2 = 0; n2 < 2; n2++)
#pragma unroll
                for (int mi = 0; mi < 4; mi++)
#pragma unroll
                    for (int kh = 0; kh < 2; kh++)
                        acc[mi][p * 2 + n2] = __builtin_amdgcn_mfma_f32_16x16x32_bf16(
                            af[mi][kh], bfp[n2][kh], acc[mi][p * 2 + n2], 0, 0, 0);
            __builtin_amdgcn_s_setprio(0);
            __builtin_amdgcn_s_barrier();
        }
    }

    const int region = blockIdx.x >> 2;          // 0=Q, 1=K, 2=V
    if (region < 2) {
        const float* bias = region ? bk : bq;
        const float oscale = region ? 1.0f : QSCALE;
        short* C = region ? Kout : Qout;
#pragma unroll
        for (int mi = 0; mi < 4; mi++) {
            int mB = m0 + wr * 64 + mi * 16 + quad * 4;
#pragma unroll
            for (int ni = 0; ni < 8; ni++) {
                int nl = (n0 + (wc * 8 + ni) * 16 + l15) & 1023;
                float bb = bias[nl];
#pragma unroll
                for (int r = 0; r < 4; r++)
                    C[(size_t)(mB + r) * HDIM + nl] =
                        f2bs((acc[mi][ni][r] + bb) * oscale);
            }
        }
    } else {                                     // V: transposed store
#pragma unroll
        for (int mi = 0; mi < 4; mi++) {
            int mB = m0 + wr * 64 + mi * 16 + quad * 4;
            int bb = mB >> 11, tt = mB & 2047;
#pragma unroll
            for (int ni = 0; ni < 8; ni++) {
                int n = n0 + (wc * 8 + ni) * 16 + l15;   // 2048..3071
                int h = (n >> 6) & 15, d = n & 63;
                float bvv = bv[n & 1023];
                size_t base = ((size_t)((bb * NHEAD + h) * DHEAD + d)) * SEQ + tt;
                ushort4 pk;
                pk.x = (unsigned short)f2bs(acc[mi][ni][0] + bvv);
                pk.y = (unsigned short)f2bs(acc[mi][ni][1] + bvv);
                pk.z = (unsigned short)f2bs(acc[mi][ni][2] + bvv);
                pk.w = (unsigned short)f2bs(acc[mi][ni][3] + bvv);
                *(ushort4*)(Vtout + base) = pk;
            }
        }
    }
}

// ---------------------------------------------------------------------------
// MFMA causal flash attention — REVERTED to the R2-proven 2-buffer form
// (41 KB -> 3 blocks/CU). Ledger: total-minus-qkv was 152.3us with this form
// vs 158us with R7's triple-buffer (57 KB -> 2/CU): attn's latency hiding
// comes from block co-residency, not deeper per-block pipelines.
// ---------------------------------------------------------------------------
__global__ __launch_bounds__(256) void attn_mfma(const short* __restrict__ Qb,
        const short* __restrict__ Kb, const short* __restrict__ Vt,
        short* __restrict__ Ab)
{
    __shared__ short SMEM[20992];        // [2][8192] K|V dbuf | Ps 4x1152
    const int tid = threadIdx.x, lane = tid & 63, w = tid >> 6;
    const int quad = lane >> 4, l15 = lane & 15;
    const int L = blockIdx.x;

    // xcd = L%8 fixed per (b,head); strip = 31-(L>>5) (longest first)
    const int pair = (L & 7) + 8 * ((L >> 3) & 3);   // 0..31
    const int strip = 31 - (L >> 5);                 // 0..31
    const int b = pair >> 4, head = pair & 15;

    const short* Kbh = Kb + (size_t)b * SEQ * HDIM + head * DHEAD;
    const short* Vth = Vt + (size_t)(b * NHEAD + head) * DHEAD * SEQ;
    short* Pw = SMEM + 16384 + w * 1152;

    const int qbase = strip * 64;
    const int qr = qbase + w * 16 + l15;

    const short* qptr = Qb + (size_t)(b * SEQ + qr) * HDIM + head * DHEAD + quad * 8;
    short8 bq0 = *(const short8*)qptr;
    short8 bq1 = *(const short8*)(qptr + 32);

    // staging pointers: 4 chunks per wave (u<8: K, u>=8: V), incremented
    const short* gp[4];
    int stp[4], ldo[4];
#pragma unroll
    for (int i = 0; i < 4; i++) {
        int u = w * 4 + i;
        if (u < 8) {
            int t = u >> 1, h = u & 1;
            gp[i] = Kbh + (size_t)(t * 16 + l15) * HDIM + h * 32 + quad * 8;
            stp[i] = 64 * HDIM;
        } else {
            int c = u - 8, dt = c >> 1, kh = c & 1;
            gp[i] = Vth + (size_t)(dt * 16 + l15) * SEQ + kh * 32 + quad * 8;
            stp[i] = 64;
        }
        ldo[i] = u * 512;
    }

    f32x4 o[4];
#pragma unroll
    for (int dt = 0; dt < 4; dt++) o[dt] = (f32x4){0.f, 0.f, 0.f, 0.f};
    float psum = 0.f;                    // per-lane partial sum of 2^s

    // prologue: stage tile 0 into buffer 0
#pragma unroll
    for (int i = 0; i < 4; i++) { gload16(gp[i], &SMEM[ldo[i]]); gp[i] += stp[i]; }

    for (int it = 0; it <= strip; ++it) {
        const int cur = it & 1;
        short* Ks = &SMEM[cur * 8192];
        short* Vs = Ks + 4096;

        if (it < strip) {                // prefetch next tile into other buf
            short* nb = &SMEM[(cur ^ 1) * 8192];
#pragma unroll
            for (int i = 0; i < 4; i++) { gload16(gp[i], nb + ldo[i]); gp[i] += stp[i]; }
            asm volatile("s_waitcnt vmcnt(4)" ::: "memory");   // tile(it) landed
        } else {
            asm volatile("s_waitcnt vmcnt(0)" ::: "memory");
        }
        __builtin_amdgcn_s_barrier();    // all waves' tile(it) visible,
                                         // prev compute done (end barrier)
        const int s0 = it * 64;
        f32x4 sv[4];
        __builtin_amdgcn_s_setprio(1);
#pragma unroll
        for (int t = 0; t < 4; t++) {
            sv[t] = (f32x4){0.f, 0.f, 0.f, 0.f};
            short8 k0 = *(const short8*)&Ks[(t * 2) * 512 + lane * 8];
            short8 k1 = *(const short8*)&Ks[(t * 2 + 1) * 512 + lane * 8];
            sv[t] = __builtin_amdgcn_mfma_f32_16x16x32_bf16(k0, bq0, sv[t], 0, 0, 0);
            sv[t] = __builtin_amdgcn_mfma_f32_16x16x32_bf16(k1, bq1, sv[t], 0, 0, 0);
        }
        __builtin_amdgcn_s_setprio(0);

        float p[16];
        if (it == strip) {
#pragma unroll
            for (int t = 0; t < 4; t++)
#pragma unroll
                for (int r = 0; r < 4; r++) {
                    int key = s0 + t * 16 + quad * 4 + r;
                    p[t * 4 + r] = (key <= qr) ? EXP2F(sv[t][r]) : 0.f;
                }
        } else {
#pragma unroll
            for (int t = 0; t < 4; t++)
#pragma unroll
                for (int r = 0; r < 4; r++)
                    p[t * 4 + r] = EXP2F(sv[t][r]);
        }
#pragma unroll
        for (int i = 0; i < 16; i++) psum += p[i];

#pragma unroll
        for (int t = 0; t < 4; t++) {
            uint2 u2;
            u2.x = pk2(p[t * 4],     p[t * 4 + 1]);
            u2.y = pk2(p[t * 4 + 2], p[t * 4 + 3]);
            *(uint2*)&Pw[l15 * 72 + t * 16 + quad * 4] = u2;
        }
        short8 bp0 = *(const short8*)&Pw[l15 * 72 + quad * 8];
        short8 bp1 = *(const short8*)&Pw[l15 * 72 + 32 + quad * 8];

        __builtin_amdgcn_s_setprio(1);
#pragma unroll
        for (int dt = 0; dt < 4; dt++) {
            short8 av0 = *(const short8*)&Vs[(dt * 2) * 512 + lane * 8];
            short8 av1 = *(const short8*)&Vs[(dt * 2 + 1) * 512 + lane * 8];
            o[dt] = __builtin_amdgcn_mfma_f32_16x16x32_bf16(av0, bp0, o[dt], 0, 0, 0);
            o[dt] = __builtin_amdgcn_mfma_f32_16x16x32_bf16(av1, bp1, o[dt], 0, 0, 0);
        }
        __builtin_amdgcn_s_setprio(0);
        __builtin_amdgcn_s_barrier();    // all reads of buf(cur) done before
                                         // next iter's prefetch overwrites it
    }

    float lrow = psum + __shfl_xor(psum, 16);
    lrow += __shfl_xor(lrow, 32);
    const float inv = 1.f / lrow;

    const size_t obase = (size_t)(b * SEQ + qr) * HDIM + head * DHEAD;
#pragma unroll
    for (int dt = 0; dt < 4; dt++) {
        uint2 u2;
        u2.x = pk2(o[dt][0] * inv, o[dt][1] * inv);
        u2.y = pk2(o[dt][2] * inv, o[dt][3] * inv);
        *(uint2*)&Ab[obase + dt * 16 + quad * 4] = u2;
    }
}

// ---------------------------------------------------------------------------
// O projection — REVERTED to the R2-proven BK=64 double-buffered form
// (16 K-iterations instead of 32; per-iteration cost is latency-pinned, so
// halving the count beats deeper buffering). 64x128 tile, grid (8,64),
// LDS 48 KB, counted vmcnt(6). ONLY writer of d_out.
// ---------------------------------------------------------------------------
__global__ __launch_bounds__(256) void gemm_o(const short* __restrict__ A,
        const short* __restrict__ Bt, const float* __restrict__ bo,
        float* __restrict__ Out)
{
    __shared__ short SM[2 * 12288];  // [buf][As 4096 | Bs 8192] = 48 KB
    const int tid = threadIdx.x, lane = tid & 63, w = tid >> 6;
    const int quad = lane >> 4, l15 = lane & 15;
    const int m0 = blockIdx.y * 64, n0 = blockIdx.x * 128;
    const int wr = w >> 1, wc = w & 1;

    const short* gsrc[6];
    short* ldst[6];
#pragma unroll
    for (int i = 0; i < 6; i++) {
        int u = w * 6 + i;
        if (u < 8) {
            int mi = u >> 1, kh = u & 1;
            gsrc[i] = A + (size_t)(m0 + mi * 16 + l15) * HDIM + kh * 32 + quad * 8;
            ldst[i] = &SM[u * 512];
        } else {
            int v = u - 8, ni = v >> 1, kh = v & 1;
            gsrc[i] = Bt + (size_t)(n0 + ni * 16 + l15) * HDIM + kh * 32 + quad * 8;
            ldst[i] = &SM[4096 + v * 512];
        }
    }

    f32x4 acc[2][4];
#pragma unroll
    for (int i = 0; i < 2; i++)
#pragma unroll
        for (int j = 0; j < 4; j++) acc[i][j] = (f32x4){0.f, 0.f, 0.f, 0.f};

    // prologue: stage tile 0 into buffer 0
#pragma unroll
    for (int i = 0; i < 6; i++) { gload16(gsrc[i], ldst[i]); gsrc[i] += 64; }

    for (int kk = 0; kk < 16; ++kk) {
        const int cur = kk & 1;
        if (kk < 15) {
            const int nb = (cur ^ 1) * 12288;
#pragma unroll
            for (int i = 0; i < 6; i++) { gload16(gsrc[i], ldst[i] + nb); gsrc[i] += 64; }
            asm volatile("s_waitcnt vmcnt(6)" ::: "memory");   // tile(kk) landed
        } else {
            asm volatile("s_waitcnt vmcnt(0)" ::: "memory");
        }
        __builtin_amdgcn_s_barrier();

        const short* Asb = &SM[cur * 12288];
        const short* Bsb = Asb + 4096;
#pragma unroll
        for (int kh = 0; kh < 2; kh++) {
            short8 af[2], bfr[4];
#pragma unroll
            for (int mi = 0; mi < 2; mi++)
                af[mi] = *(const short8*)&Asb[((wr * 2 + mi) * 2 + kh) * 512 + lane * 8];
#pragma unroll
            for (int ni = 0; ni < 4; ni++)
                bfr[ni] = *(const short8*)&Bsb[((wc * 4 + ni) * 2 + kh) * 512 + lane * 8];
#pragma unroll
            for (int mi = 0; mi < 2; mi++)
#pragma unroll
                for (int ni = 0; ni < 4; ni++)
                    acc[mi][ni] = __builtin_amdgcn_mfma_f32_16x16x32_bf16(
                                      af[mi], bfr[ni], acc[mi][ni], 0, 0, 0);
        }
        __builtin_amdgcn_s_barrier();
    }

#pragma unroll
    for (int mi = 0; mi < 2; mi++) {
        int mB = m0 + (wr * 2 + mi) * 16 + quad * 4;
#pragma unroll
        for (int ni = 0; ni < 4; ni++) {
            int n = n0 + (wc * 4 + ni) * 16 + l15;
            float bb = bo[n];
#pragma unroll
            for (int r = 0; r < 4; r++)
                Out[(size_t)(mB + r) * HDIM + n] = acc[mi][ni][r] + bb;
        }
    }
}

// ---------------------------------------------------------------------------
extern "C" void kernel_launch(void* const* d_in, const int* in_sizes, int n_in,
                              void* d_out, int out_size, void* d_ws, size_t ws_size,
                              hipStream_t stream)
{
    const float* src = (const float*)d_in[0];
    const float* Wq = (const float*)d_in[2];
    const float* bq = (const float*)d_in[3];
    const float* Wk = (const float*)d_in[4];
    const float* bk = (const float*)d_in[5];
    const float* Wv = (const float*)d_in[6];
    const float* bv = (const float*)d_in[7];
    const float* Wo = (const float*)d_in[8];
    const float* bo = (const float*)d_in[9];
    float* out = (float*)d_out;

    // ws (34 MB): [Sb 8][Qb 8][Kb 8][Vt 8][WoT slot 2]
    // Merged transposed QKV weights WT (3072x1024 bf16 = 6 MB) live in d_out
    // (16 MB fp32), which is dead scratch until gemm_o fully overwrites it.
    short* Sb   = (short*)d_ws;
    short* Qb   = Sb + (size_t)MROWS * HDIM;
    short* Kb   = Qb + (size_t)MROWS * HDIM;
    short* Vt   = Kb + (size_t)MROWS * HDIM;
    short* WoT  = Vt + (size_t)MROWS * HDIM;   // 2 MB slot
    short* WT   = (short*)d_out;               // 6 MB scratch in out buffer
    short* Ab   = Qb;                          // attention output over Q

    prep1<<<dim3(4096 + 1024), dim3(256), 0, stream>>>(src, Wq, Wk, Wv, Wo, Sb, WT, WoT);

    gemm_qkv<<<dim3(12, 16), dim3(512), 0, stream>>>(Sb, WT, bq, bk, bv, Qb, Kb, Vt);

    attn_mfma<<<dim3(1024), dim3(256), 0, stream>>>(Qb, Kb, Vt, Ab);

    gemm_o<<<dim3(8, 64), dim3(256), 0, stream>>>(Ab, WoT, bo, out);
}